// Round 1
// baseline (148.347 us; speedup 1.0000x reference)
//
#include <hip/hip_runtime.h>
#include <hip/hip_bf16.h>
#include <math.h>

// Problem constants (fixed by reference setup_inputs)
#define BN 8192       // batch
#define DK 256        // embedding dim (= GEMM K)
#define TM 128        // row/col tile
#define NSLICE 8      // column slices (blocks in y)
#define SLICE_TILES 8 // 8 x 128 cols = 1024 cols per slice
#define INV_T 1.42857142857142857f  // 1/0.7, also the fixed softmax shift m

using bf16x8 = __attribute__((ext_vector_type(8))) short;  // 8 bf16 = 4 VGPRs
using f32x4  = __attribute__((ext_vector_type(4))) float;

__device__ __forceinline__ void async_copy16(void* lds, const void* g) {
  __builtin_amdgcn_global_load_lds(
      (const __attribute__((address_space(1))) unsigned int*)g,
      (__attribute__((address_space(3))) unsigned int*)lds,
      16, 0, 0);
}

// ---------------- Kernel 1: L2-normalize rows, fp32 -> bf16 ----------------
__global__ void norm_kernel(const float* __restrict__ E, unsigned short* __restrict__ Eb) {
  const int row = blockIdx.x;
  const int t = threadIdx.x;              // 256 threads, one element each
  float x = E[row * DK + t];
  float ss = x * x;
#pragma unroll
  for (int m = 32; m >= 1; m >>= 1) ss += __shfl_xor(ss, m);
  __shared__ float wsum[4];
  const int wv = t >> 6, lane = t & 63;
  if (lane == 0) wsum[wv] = ss;
  __syncthreads();
  const float tot = wsum[0] + wsum[1] + wsum[2] + wsum[3];
  const float scale = 1.0f / fmaxf(sqrtf(tot), 1e-12f);
  __hip_bfloat16 h = __float2bfloat16(x * scale);
  Eb[row * DK + t] = *(unsigned short*)&h;
}

// ---------------- Kernel 2: fused sims + masked max / sum-exp ----------------
// Block = 256 thr (4 waves, 2x2 of 64x64 wave tiles), computes rows
// [blockIdx.x*128, +128) against cols [blockIdx.y*1024, +1024).
// A tile persistent in LDS (64 KB); B staged in BK=64 chunks (16 KB).
// LDS = 80 KB exactly -> 2 blocks/CU.
__launch_bounds__(256, 2)
__global__ void contrast_kernel(const unsigned short* __restrict__ Eb,
                                const int* __restrict__ cat,
                                float* __restrict__ posPart,
                                float* __restrict__ negPart) {
  __shared__ __align__(16) unsigned short As[TM * DK];  // 64 KB, [row][k]
  __shared__ __align__(16) unsigned short Bs[TM * 64];  // 16 KB, [col][k-chunk]

  const int tid = threadIdx.x;
  const int lane = tid & 63;
  const int wv = tid >> 6;
  const int wm = wv >> 1;      // wave row (0..1)
  const int wn = wv & 1;       // wave col (0..1)
  const int quad = lane >> 4;
  const int l16 = lane & 15;
  const int rowBase = blockIdx.x * TM;
  const int colBase0 = blockIdx.y * (TM * SLICE_TILES);

  // ---- stage A tile: 64 KB contiguous global -> contiguous LDS ----
  {
    const char* g = (const char*)(Eb + (size_t)rowBase * DK);
    char* l = (char*)As;
#pragma unroll
    for (int i = 0; i < 16; ++i)
      async_copy16(l + tid * 16 + i * 4096, g + tid * 16 + i * 4096);
  }

  // Rows owned by this lane (C layout: col=lane&15, row=quad*4+reg):
  int rowIdx[16];
  int catRow[16];
  float posmx[16], negsm[16];
#pragma unroll
  for (int ti = 0; ti < 4; ++ti)
#pragma unroll
    for (int r = 0; r < 4; ++r) {
      const int si = ti * 4 + r;
      rowIdx[si] = rowBase + wm * 64 + ti * 16 + quad * 4 + r;
      catRow[si] = cat[rowIdx[si]];
      posmx[si] = -1e30f;
      negsm[si] = 0.0f;
    }

#pragma unroll 1
  for (int ct = 0; ct < SLICE_TILES; ++ct) {
    const int colBase = colBase0 + ct * TM;

    f32x4 acc[4][4];
#pragma unroll
    for (int ti = 0; ti < 4; ++ti)
#pragma unroll
      for (int tj = 0; tj < 4; ++tj)
        acc[ti][tj] = f32x4{0.f, 0.f, 0.f, 0.f};

#pragma unroll 1
    for (int kc = 0; kc < 4; ++kc) {
      __syncthreads();  // prev Bs consumers done (first iter: covers A wait too)
      {
        // thread -> (col = tid>>3 (+32/iter), 16B of k-chunk kc)
        const char* g = (const char*)Eb +
                        (size_t)(colBase + (tid >> 3)) * (DK * 2) +
                        kc * 128 + (tid & 7) * 16;
        char* l = (char*)Bs + tid * 16;
#pragma unroll
        for (int it = 0; it < 4; ++it)
          async_copy16(l + it * 4096, g + (size_t)it * 32 * (DK * 2));
      }
      __syncthreads();  // Bs ready (barrier drains vmcnt)

#pragma unroll
      for (int s = 0; s < 2; ++s) {
        bf16x8 a[4], b[4];
#pragma unroll
        for (int ti = 0; ti < 4; ++ti)
          a[ti] = *(const bf16x8*)&As[(wm * 64 + ti * 16 + l16) * DK + kc * 64 + s * 32 + quad * 8];
#pragma unroll
        for (int tj = 0; tj < 4; ++tj)
          b[tj] = *(const bf16x8*)&Bs[(wn * 64 + tj * 16 + l16) * 64 + s * 32 + quad * 8];
#pragma unroll
        for (int ti = 0; ti < 4; ++ti)
#pragma unroll
          for (int tj = 0; tj < 4; ++tj)
            acc[ti][tj] = __builtin_amdgcn_mfma_f32_16x16x32_bf16(a[ti], b[tj], acc[ti][tj], 0, 0, 0);
      }
    }

    // ---- fused epilogue for this 128x128 tile (acc = raw cosines) ----
    int catCol[4], colIdx[4];
#pragma unroll
    for (int tj = 0; tj < 4; ++tj) {
      colIdx[tj] = colBase + wn * 64 + tj * 16 + l16;
      catCol[tj] = cat[colIdx[tj]];
    }
#pragma unroll
    for (int ti = 0; ti < 4; ++ti)
#pragma unroll
      for (int r = 0; r < 4; ++r) {
        const int si = ti * 4 + r;
        float pm = posmx[si];
        float ns = negsm[si];
#pragma unroll
        for (int tj = 0; tj < 4; ++tj) {
          const float v = acc[ti][tj][r];
          const bool same = (catRow[si] == catCol[tj]);
          const bool self = (rowIdx[si] == colIdx[tj]);
          // negatives: exp(v/T - m_fixed) with m_fixed = 1/T
          const float e = __expf(__fmaf_rn(v, INV_T, -INV_T));
          ns += same ? 0.0f : e;
          // positives: track raw cosine max (monotone under *1/T)
          pm = (same && !self) ? fmaxf(pm, v) : pm;
        }
        posmx[si] = pm;
        negsm[si] = ns;
      }
  }

  // ---- reduce across the 16 lanes sharing each row (cols split) ----
#pragma unroll
  for (int si = 0; si < 16; ++si) {
    float pm = posmx[si], ns = negsm[si];
#pragma unroll
    for (int m = 1; m < 16; m <<= 1) {
      pm = fmaxf(pm, __shfl_xor(pm, m));
      ns += __shfl_xor(ns, m);
    }
    posmx[si] = pm;
    negsm[si] = ns;
  }

  // ---- combine the wn=0 / wn=1 wave halves via LDS (reuse As) ----
  float* red = (float*)As;  // [0..127]=pos, [128..255]=neg
  __syncthreads();
  if (wn == 1 && l16 == 0) {
#pragma unroll
    for (int si = 0; si < 16; ++si) {
      const int rl = wm * 64 + (si >> 2) * 16 + quad * 4 + (si & 3);
      red[rl] = posmx[si];
      red[128 + rl] = negsm[si];
    }
  }
  __syncthreads();
  if (wn == 0 && l16 == 0) {
#pragma unroll
    for (int si = 0; si < 16; ++si) {
      const int rl = wm * 64 + (si >> 2) * 16 + quad * 4 + (si & 3);
      const float pm = fmaxf(posmx[si], red[rl]);
      const float ns = negsm[si] + red[128 + rl];
      posPart[(size_t)(rowBase + rl) * NSLICE + blockIdx.y] = pm;  // raw cosine max
      negPart[(size_t)(rowBase + rl) * NSLICE + blockIdx.y] = ns;
    }
  }
}

// ---------------- Kernel 3: combine slices, per-row loss, mean ----------------
__global__ void finalize_kernel(const float* __restrict__ posPart,
                                const float* __restrict__ negPart,
                                float* __restrict__ out) {
  const int tid = threadIdx.x;  // 256 threads
  float total = 0.0f;
  int cnt = 0;
  for (int row = tid; row < BN; row += 256) {
    float pm = -1e30f, ns = 0.0f;
#pragma unroll
    for (int s = 0; s < NSLICE; ++s) {
      pm = fmaxf(pm, posPart[row * NSLICE + s]);
      ns += negPart[row * NSLICE + s];
    }
    if (pm > -1e29f && ns > 0.0f) {   // valid: has positive AND negative
      const float pos = pm * INV_T;
      const float lse = INV_T + logf(expf(pos - INV_T) + ns);
      total += lse - pos;
      cnt += 1;
    }
  }
#pragma unroll
  for (int m = 1; m < 64; m <<= 1) {
    total += __shfl_xor(total, m);
    cnt += __shfl_xor(cnt, m);
  }
  __shared__ float sT[4];
  __shared__ int sC[4];
  const int wv = tid >> 6, lane = tid & 63;
  if (lane == 0) { sT[wv] = total; sC[wv] = cnt; }
  __syncthreads();
  if (tid == 0) {
    const float T = sT[0] + sT[1] + sT[2] + sT[3];
    const int C = sC[0] + sC[1] + sC[2] + sC[3];
    out[0] = (C > 0) ? T / (float)C : 0.0f;
  }
}

extern "C" void kernel_launch(void* const* d_in, const int* in_sizes, int n_in,
                              void* d_out, int out_size, void* d_ws, size_t ws_size,
                              hipStream_t stream) {
  const float* E = (const float*)d_in[0];
  const int* cat = (const int*)d_in[1];
  // d_in[2] (font_labels) unused by the reference.

  // Workspace layout: [0,4MB) bf16 normalized embeddings; then partials.
  unsigned short* Eb = (unsigned short*)d_ws;
  float* posPart = (float*)((char*)d_ws + (size_t)BN * DK * 2);
  float* negPart = posPart + (size_t)BN * NSLICE;
  float* out = (float*)d_out;

  hipLaunchKernelGGL(norm_kernel, dim3(BN), dim3(DK), 0, stream, E, Eb);
  hipLaunchKernelGGL(contrast_kernel, dim3(BN / TM, NSLICE), dim3(256), 0, stream,
                     Eb, cat, posPart, negPart);
  hipLaunchKernelGGL(finalize_kernel, dim3(1), dim3(256), 0, stream,
                     posPart, negPart, out);
}

// Round 2
// 117.270 us; speedup vs baseline: 1.2650x; 1.2650x over previous
//
#include <hip/hip_runtime.h>
#include <hip/hip_bf16.h>
#include <math.h>

// Problem constants (fixed by reference setup_inputs)
#define BN 8192       // batch
#define DK 256        // embedding dim (= GEMM K)
#define TM 128        // row/col tile
#define NSLICE 8      // column slices (blocks in y)
#define SLICE_TILES 8 // 8 x 128 cols = 1024 cols per slice
#define INV_T 1.42857142857142857f  // 1/0.7, also the fixed softmax shift m

using bf16x8 = __attribute__((ext_vector_type(8))) short;  // 8 bf16 = 4 VGPRs
using f32x4  = __attribute__((ext_vector_type(4))) float;

__device__ __forceinline__ void async_copy16(void* lds, const void* g) {
  __builtin_amdgcn_global_load_lds(
      (const __attribute__((address_space(1))) unsigned int*)g,
      (__attribute__((address_space(3))) unsigned int*)lds,
      16, 0, 0);
}

// ---------------- Kernel 1: L2-normalize rows, fp32 -> bf16 ----------------
// One wave per row: float4 loads, shuffle reduce, ushort4 stores. No LDS.
__global__ void norm_kernel(const float* __restrict__ E, unsigned short* __restrict__ Eb) {
  const int wv = threadIdx.x >> 6, lane = threadIdx.x & 63;
  const int row = blockIdx.x * 4 + wv;
  const float4 x = *(const float4*)&E[(size_t)row * DK + lane * 4];
  float ss = x.x * x.x + x.y * x.y + x.z * x.z + x.w * x.w;
#pragma unroll
  for (int m = 1; m < 64; m <<= 1) ss += __shfl_xor(ss, m);
  const float scale = 1.0f / fmaxf(sqrtf(ss), 1e-12f);
  ushort4 o;
  __hip_bfloat16 h0 = __float2bfloat16(x.x * scale); o.x = *(unsigned short*)&h0;
  __hip_bfloat16 h1 = __float2bfloat16(x.y * scale); o.y = *(unsigned short*)&h1;
  __hip_bfloat16 h2 = __float2bfloat16(x.z * scale); o.z = *(unsigned short*)&h2;
  __hip_bfloat16 h3 = __float2bfloat16(x.w * scale); o.w = *(unsigned short*)&h3;
  *(ushort4*)&Eb[(size_t)row * DK + lane * 4] = o;
}

// ---------------- Kernel 2: fused sims + masked max / sum-exp ----------------
// Block = 256 thr (4 waves, 2x2 of 64x64 wave tiles), rows [bx*128,+128) vs
// cols [by*1024,+1024). A persistent in LDS (64 KB), B staged in BK=64 chunks
// (16 KB). LDS = 80 KB -> 2 blocks/CU.
// LDS XOR swizzle (16B-chunk granularity): LDS(row, c) holds global chunk
// c ^ (row & 7). Breaks the 16-way bank conflict of the power-of-2 row
// strides (512B / 128B) while keeping global_load_lds's contiguous-LDS
// constraint; global access stays within 128B lines (full-line coalescing).
__launch_bounds__(256, 2)
__global__ void contrast_kernel(const unsigned short* __restrict__ Eb,
                                const int* __restrict__ cat,
                                float* __restrict__ posPart,
                                float* __restrict__ negPart) {
  __shared__ __align__(16) unsigned short As[TM * DK];  // 64 KB, [row][k] swizzled
  __shared__ __align__(16) unsigned short Bs[TM * 64];  // 16 KB, [col][k-chunk] swizzled

  const int tid = threadIdx.x;
  const int lane = tid & 63;
  const int wv = tid >> 6;
  const int wm = wv >> 1;      // wave row (0..1)
  const int wn = wv & 1;       // wave col (0..1)
  const int quad = lane >> 4;
  const int l16 = lane & 15;
  const int sw = l16 & 7;      // per-lane swizzle key (row&7 == l16&7)
  const int rowBase = blockIdx.x * TM;
  const int colBase0 = blockIdx.y * (TM * SLICE_TILES);

  // ---- stage A tile: 64 KB, swizzled source ----
  {
    const char* gbase = (const char*)(Eb + (size_t)rowBase * DK);
#pragma unroll
    for (int i = 0; i < 16; ++i) {
      const int chunk = tid + i * 256;   // LDS 16B-chunk index (lane-contiguous)
      const int row = chunk >> 5;        // 32 chunks per 512B row
      const int c = chunk & 31;
      async_copy16((char*)As + chunk * 16,
                   gbase + row * 512 + (c ^ (row & 7)) * 16);
    }
  }

  // Rows owned by this lane (C layout: col=lane&15, row=quad*4+reg):
  int rowIdx[16];
  int catRow[16];
  float posmx[16], negsm[16];
#pragma unroll
  for (int ti = 0; ti < 4; ++ti)
#pragma unroll
    for (int r = 0; r < 4; ++r) {
      const int si = ti * 4 + r;
      rowIdx[si] = rowBase + wm * 64 + ti * 16 + quad * 4 + r;
      catRow[si] = cat[rowIdx[si]];
      posmx[si] = -1e30f;
      negsm[si] = 0.0f;
    }

#pragma unroll 1
  for (int ct = 0; ct < SLICE_TILES; ++ct) {
    const int colBase = colBase0 + ct * TM;

    f32x4 acc[4][4];
#pragma unroll
    for (int ti = 0; ti < 4; ++ti)
#pragma unroll
      for (int tj = 0; tj < 4; ++tj)
        acc[ti][tj] = f32x4{0.f, 0.f, 0.f, 0.f};

#pragma unroll 1
    for (int kc = 0; kc < 4; ++kc) {
      __syncthreads();  // prev Bs consumers done (first iter: covers A wait too)
      {
        const int col8 = tid >> 3;   // col within tile (+32 per it)
        const int c = tid & 7;       // 16B chunk within 128B k-slab
        const char* g = (const char*)Eb +
                        (size_t)(colBase + col8) * 512 +
                        kc * 128 + ((c ^ (col8 & 7)) * 16);
        char* l = (char*)Bs + tid * 16;
#pragma unroll
        for (int it = 0; it < 4; ++it)   // col8+32: (col8&7) unchanged
          async_copy16(l + it * 4096, g + (size_t)it * 32 * 512);
      }
      __syncthreads();  // Bs ready (barrier drains vmcnt)

#pragma unroll
      for (int s = 0; s < 2; ++s) {
        bf16x8 a[4], b[4];
#pragma unroll
        for (int ti = 0; ti < 4; ++ti)
          a[ti] = *(const bf16x8*)&As[(wm * 64 + ti * 16 + l16) * DK +
                                      (((kc * 8 + s * 4 + quad) ^ sw) << 3)];
#pragma unroll
        for (int tj = 0; tj < 4; ++tj)
          b[tj] = *(const bf16x8*)&Bs[(wn * 64 + tj * 16 + l16) * 64 +
                                      (((s * 4 + quad) ^ sw) << 3)];
#pragma unroll
        for (int ti = 0; ti < 4; ++ti)
#pragma unroll
          for (int tj = 0; tj < 4; ++tj)
            acc[ti][tj] = __builtin_amdgcn_mfma_f32_16x16x32_bf16(a[ti], b[tj], acc[ti][tj], 0, 0, 0);
      }
    }

    // ---- fused epilogue for this 128x128 tile (acc = raw cosines) ----
    int catCol[4], colIdx[4];
#pragma unroll
    for (int tj = 0; tj < 4; ++tj) {
      colIdx[tj] = colBase + wn * 64 + tj * 16 + l16;
      catCol[tj] = cat[colIdx[tj]];
    }
#pragma unroll
    for (int ti = 0; ti < 4; ++ti)
#pragma unroll
      for (int r = 0; r < 4; ++r) {
        const int si = ti * 4 + r;
        float pm = posmx[si];
        float ns = negsm[si];
#pragma unroll
        for (int tj = 0; tj < 4; ++tj) {
          const float v = acc[ti][tj][r];
          const bool same = (catRow[si] == catCol[tj]);
          const bool self = (rowIdx[si] == colIdx[tj]);
          const float e = __expf(__fmaf_rn(v, INV_T, -INV_T));
          ns += same ? 0.0f : e;
          pm = (same && !self) ? fmaxf(pm, v) : pm;
        }
        posmx[si] = pm;
        negsm[si] = ns;
      }
  }

  // ---- reduce across the 16 lanes sharing each row (cols split) ----
#pragma unroll
  for (int si = 0; si < 16; ++si) {
    float pm = posmx[si], ns = negsm[si];
#pragma unroll
    for (int m = 1; m < 16; m <<= 1) {
      pm = fmaxf(pm, __shfl_xor(pm, m));
      ns += __shfl_xor(ns, m);
    }
    posmx[si] = pm;
    negsm[si] = ns;
  }

  // ---- combine the wn=0 / wn=1 wave halves via LDS (reuse As) ----
  float* red = (float*)As;  // [0..127]=pos, [128..255]=neg
  __syncthreads();
  if (wn == 1 && l16 == 0) {
#pragma unroll
    for (int si = 0; si < 16; ++si) {
      const int rl = wm * 64 + (si >> 2) * 16 + quad * 4 + (si & 3);
      red[rl] = posmx[si];
      red[128 + rl] = negsm[si];
    }
  }
  __syncthreads();
  if (wn == 0 && l16 == 0) {
#pragma unroll
    for (int si = 0; si < 16; ++si) {
      const int rl = wm * 64 + (si >> 2) * 16 + quad * 4 + (si & 3);
      const float pm = fmaxf(posmx[si], red[rl]);
      const float ns = negsm[si] + red[128 + rl];
      posPart[(size_t)(rowBase + rl) * NSLICE + blockIdx.y] = pm;  // raw cosine max
      negPart[(size_t)(rowBase + rl) * NSLICE + blockIdx.y] = ns;
    }
  }
}

// ---------------- Kernel 3a: per-row loss, atomic accumulate ----------------
// Grid 32 x 256: one thread per row, float4 loads (coalesced 32B/row/array).
__global__ void finalize1_kernel(const float* __restrict__ posPart,
                                 const float* __restrict__ negPart,
                                 float* __restrict__ accum) {
  const int tid = threadIdx.x;
  const int row = blockIdx.x * 256 + tid;
  const float4 p0 = *(const float4*)&posPart[row * NSLICE];
  const float4 p1 = *(const float4*)&posPart[row * NSLICE + 4];
  const float4 n0 = *(const float4*)&negPart[row * NSLICE];
  const float4 n1 = *(const float4*)&negPart[row * NSLICE + 4];
  const float pm = fmaxf(fmaxf(fmaxf(p0.x, p0.y), fmaxf(p0.z, p0.w)),
                         fmaxf(fmaxf(p1.x, p1.y), fmaxf(p1.z, p1.w)));
  const float ns = (n0.x + n0.y + n0.z + n0.w) + (n1.x + n1.y + n1.z + n1.w);
  float loss = 0.0f, c = 0.0f;
  if (pm > -1e29f && ns > 0.0f) {   // valid: has positive AND negative
    const float pos = pm * INV_T;
    const float lse = INV_T + logf(expf(pos - INV_T) + ns);
    loss = lse - pos;
    c = 1.0f;
  }
#pragma unroll
  for (int m = 1; m < 64; m <<= 1) {
    loss += __shfl_xor(loss, m);
    c += __shfl_xor(c, m);
  }
  __shared__ float sL[4], sC[4];
  const int wv = tid >> 6, lane = tid & 63;
  if (lane == 0) { sL[wv] = loss; sC[wv] = c; }
  __syncthreads();
  if (tid == 0) {
    atomicAdd(&accum[0], sL[0] + sL[1] + sL[2] + sL[3]);
    atomicAdd(&accum[1], sC[0] + sC[1] + sC[2] + sC[3]);
  }
}

// ---------------- Kernel 3b: final division ----------------
__global__ void finalize2_kernel(const float* __restrict__ accum,
                                 float* __restrict__ out) {
  out[0] = (accum[1] > 0.0f) ? accum[0] / accum[1] : 0.0f;
}

extern "C" void kernel_launch(void* const* d_in, const int* in_sizes, int n_in,
                              void* d_out, int out_size, void* d_ws, size_t ws_size,
                              hipStream_t stream) {
  const float* E = (const float*)d_in[0];
  const int* cat = (const int*)d_in[1];
  // d_in[2] (font_labels) unused by the reference.

  // Workspace: [0,4MB) bf16 normalized embeddings; partials; 8B accumulator.
  unsigned short* Eb = (unsigned short*)d_ws;
  float* posPart = (float*)((char*)d_ws + (size_t)BN * DK * 2);
  float* negPart = posPart + (size_t)BN * NSLICE;
  float* accum = negPart + (size_t)BN * NSLICE;
  float* out = (float*)d_out;

  hipMemsetAsync(accum, 0, 2 * sizeof(float), stream);
  hipLaunchKernelGGL(norm_kernel, dim3(BN / 4), dim3(256), 0, stream, E, Eb);
  hipLaunchKernelGGL(contrast_kernel, dim3(BN / TM, NSLICE), dim3(256), 0, stream,
                     Eb, cat, posPart, negPart);
  hipLaunchKernelGGL(finalize1_kernel, dim3(BN / 256), dim3(256), 0, stream,
                     posPart, negPart, accum);
  hipLaunchKernelGGL(finalize2_kernel, dim3(1), dim3(1), 0, stream, accum, out);
}